// Round 2
// baseline (364.631 us; speedup 1.0000x reference)
//
#include <hip/hip_runtime.h>

// LengthAdaptor: B=16, T=512, C_IN=512, C_HID=256, C_EMB=384, K=5, MAX_DUR=8
// Outputs (concat, f32): x_up [16,4096,512] | ldp [16,512] | emb_up [16,4096,384]
//
// R11: revert to R9's proven structure (conv 256-thr 4-wave 32x128 tile,
// gathers at high occupancy under (256,2)), but:
//  - dispatch 3 = ln1 + emb_up gather (emb gather only needs idx; moved up)
//  - dispatch 4 = fused conv2+ln2+linear+mask, 256-thr, each wave owns TWO
//    32x32 col-chains (full 256-col LN row per block). Deletes ln2 dispatch
//    and the layer-2 hraw round trip (-16.8 MB HBM).
// 4 dispatches total. R10's full fusion regressed because shared
// launch_bounds(512,4) starved the gather of occupancy; layer-2-only fusion
// keeps gathers in their proven config.

constexpr int Bn = 16, Tn = 512, CIN1 = 512, CHID = 256, CEMB = 384, MAXMEL = 4096;
constexpr int NROWS = Bn * Tn;
#define LRELU 0.3f
#define EPSV 1e-5f

typedef __attribute__((ext_vector_type(8))) short bf16x8;
typedef __attribute__((ext_vector_type(4))) float f32x4;
typedef __attribute__((ext_vector_type(16))) float f32x16;
typedef __attribute__((ext_vector_type(4))) unsigned int u32x4;
typedef unsigned short ushort_t;

static __device__ __forceinline__ ushort_t f2bf(float f) {
  unsigned u = __builtin_bit_cast(unsigned, f);
  unsigned r = (u + 0x7fffu + ((u >> 16) & 1u)) >> 16;  // RNE
  return (ushort_t)r;
}

// ---------------------------------------------------------------------------
// Conv MFMA body (32x32x16), verbatim R9. Block tile 32 rows x 128 cols,
// 4 waves, each one 32x32 acc chain. A staged per 128-ci chunk in LDS (XOR
// swizzle); B direct from L2 (fragment-contiguous). Writes pre-activation
// f32 to hraw.
// ---------------------------------------------------------------------------
template <int CI, bool F32IN>
static __device__ __forceinline__ void conv_body(
    int mt, int ns,
    const float* __restrict__ xin, const ushort_t* __restrict__ inbf,
    const ushort_t* __restrict__ wB, float* __restrict__ hraw) {
  constexpr int NCHUNK = CI / 128;
  constexpr int ROWS = 36, LDSTRIDE = 136;
  __shared__ ushort_t sA[ROWS * LDSTRIDE];

  const int b = mt >> 4, t0 = (mt & 15) * 32;
  const int tid = threadIdx.x;
  const int l = tid & 63, nh = tid >> 6;
  const int lm = l & 31, lq = l >> 5;
  const int cob32 = ns * 4 + nh;

  f32x16 acc;
#pragma unroll
  for (int i = 0; i < 16; ++i) acc[i] = 0.f;

  const ushort_t* pB = wB + (size_t)cob32 * 512 + l * 8;

#pragma unroll 1
  for (int chunk = 0; chunk < NCHUNK; ++chunk) {
    {
      const int cibase = chunk * 128;
#pragma unroll 1
      for (int i = 0; i < 9; ++i) {
        const int p = i * 256 + tid;      // 9*256 = 2304 = 36*64 exact
        const int r = p >> 6, c2 = (p & 63) * 2;
        const int t = t0 - 2 + r;
        unsigned hv = 0;
        if ((unsigned)t < (unsigned)Tn) {
          const size_t src = (size_t)(b * Tn + t) * CI + cibase + c2;
          if (F32IN) {
            const float2 v = *(const float2*)(xin + src);
            hv = (unsigned)f2bf(v.x) | ((unsigned)f2bf(v.y) << 16);
          } else {
            hv = *(const unsigned*)(inbf + src);
          }
        }
        const int sw = ((r >> 3) & 3) << 3;
        *(unsigned*)&sA[r * LDSTRIDE + (c2 ^ sw)] = hv;
      }
    }
    __syncthreads();

#pragma unroll 1
    for (int ksh = 0; ksh < 5; ++ksh) {
      const int r = lm + ksh;
      const int sw = ((r >> 3) & 3) << 3;
      const size_t bbase = (size_t)((ksh * (CI / 16) + chunk * 8) * 8) * 512;
#pragma unroll
      for (int kk = 0; kk < 8; ++kk) {
        const int c = (kk * 16 + lq * 8) ^ sw;
        const bf16x8 a = *(const bf16x8*)&sA[r * LDSTRIDE + c];
        const bf16x8 bv = *(const bf16x8*)(pB + bbase + (size_t)kk * 8 * 512);
        acc = __builtin_amdgcn_mfma_f32_32x32x16_bf16(a, bv, acc, 0, 0, 0);
      }
    }
    __syncthreads();
  }

  // D: col = lane&31, row = (reg&3) + 8*(reg>>2) + 4*(lane>>5)
  const int col = ns * 128 + nh * 32 + lm;
  float* pOut = hraw + (size_t)(b * Tn + t0) * 256 + col;
#pragma unroll
  for (int reg = 0; reg < 16; ++reg) {
    const int row = (reg & 3) + 8 * (reg >> 2) + 4 * lq;
    pOut[(size_t)row * 256] = acc[reg];
  }
}

// ---------------------------------------------------------------------------
// Dispatch 2: conv1 (blk%3==0, 512 blocks) + x_up gather (1024 blocks).
// Grid 1536. Verbatim R9.
// ---------------------------------------------------------------------------
__global__ __launch_bounds__(256, 2) void conv1_gather_kernel(
    const float* __restrict__ x_res, const ushort_t* __restrict__ w1,
    float* __restrict__ hraw,
    const float* __restrict__ x, const int* __restrict__ idx,
    float* __restrict__ x_up) {
  const int blk = blockIdx.x;
  if (blk % 3 == 0) {
    const int cid = blk / 3;              // 0..511
    conv_body<512, true>(cid & 255, cid >> 8, x_res, nullptr, w1, hraw);
    return;
  }
  // ---- x_up gather: 1024 blocks, 2,097,152 f32x4 units (8 iters) ----
  const int gid = blk - 1 - blk / 3;      // 0..1023
  const f32x4* x4 = (const f32x4*)x;
  f32x4* xu4 = (f32x4*)x_up;
  const int tid0 = gid * 256 + threadIdx.x;
  const int stride = 1024 * 256;
  const f32x4 z = (f32x4){0.f, 0.f, 0.f, 0.f};
  for (int u = tid0; u < Bn * MAXMEL * 128; u += stride) {
    const int bp = u >> 7, i = u & 127;
    const int t = idx[bp];
    const int b = bp >> 12;
    const f32x4 v = (t >= 0) ? x4[((b << 9) + t) * 128 + i] : z;
    __builtin_nontemporal_store(v, &xu4[u]);
  }
}

// ---------------------------------------------------------------------------
// Dispatch 3: ln1 (bias+leakyrelu+LN -> h1 bf16; 2048 logical blocks) +
// emb_up gather (1024 logical blocks). Grid 3072, 1:2 interleave so the
// streaming gather and the hraw-reading LN mix across CUs.
// ---------------------------------------------------------------------------
__global__ __launch_bounds__(256, 2) void ln1_emb_kernel(
    const float* __restrict__ hraw,       // [8192][256] f32
    const float* __restrict__ bias, const float* __restrict__ g,
    const float* __restrict__ be, ushort_t* __restrict__ h1,
    const float* __restrict__ emb, const int* __restrict__ idx,
    float* __restrict__ emb_up) {
  const int blk = blockIdx.x;
  if (blk % 3 != 2) {
    // ---- ln1 path: lid 0..2047, 4 rows per block ----
    const int lid = (blk / 3) * 2 + (blk % 3);
    const int row = lid * 4 + (threadIdx.x >> 6);
    const int l = threadIdx.x & 63;
    const f32x4 p = ((const f32x4*)hraw)[row * 64 + l];
    const f32x4 bi = ((const f32x4*)bias)[l];
    float v0 = p.x + bi.x, v1 = p.y + bi.y, v2 = p.z + bi.z, v3 = p.w + bi.w;
    v0 = (v0 > 0.f) ? v0 : LRELU * v0;
    v1 = (v1 > 0.f) ? v1 : LRELU * v1;
    v2 = (v2 > 0.f) ? v2 : LRELU * v2;
    v3 = (v3 > 0.f) ? v3 : LRELU * v3;
    float s = v0 + v1 + v2 + v3;
    float s2 = v0 * v0 + v1 * v1 + v2 * v2 + v3 * v3;
#pragma unroll
    for (int off = 32; off >= 1; off >>= 1) {
      s += __shfl_xor(s, off);
      s2 += __shfl_xor(s2, off);
    }
    const float mu = s * (1.f / 256.f);
    const float var = s2 * (1.f / 256.f) - mu * mu;
    const float rs = rsqrtf(var + EPSV);
    const f32x4 gg = ((const f32x4*)g)[l];
    const f32x4 bb = ((const f32x4*)be)[l];
    ushort4 uh;
    uh.x = f2bf((v0 - mu) * rs * gg.x + bb.x);
    uh.y = f2bf((v1 - mu) * rs * gg.y + bb.y);
    uh.z = f2bf((v2 - mu) * rs * gg.z + bb.z);
    uh.w = f2bf((v3 - mu) * rs * gg.w + bb.w);
    ((ushort4*)h1)[row * 64 + l] = uh;
    return;
  }
  // ---- emb_up gather: gid 0..1023, 1,572,864 f32x4 units (6 iters) ----
  const int gid = blk / 3;
  const f32x4* e4 = (const f32x4*)emb;
  f32x4* eu4 = (f32x4*)emb_up;
  const int tid0 = gid * 256 + threadIdx.x;
  const int stride = 1024 * 256;
  const f32x4 z = (f32x4){0.f, 0.f, 0.f, 0.f};
  for (int u = tid0; u < Bn * MAXMEL * 96; u += stride) {
    const int bp = u / 96, i = u - bp * 96;
    const int t = idx[bp];
    const int b = bp >> 12;
    const f32x4 v = (t >= 0) ? e4[((b << 9) + t) * 96 + i] : z;
    __builtin_nontemporal_store(v, &eu4[u]);
  }
}

// ---------------------------------------------------------------------------
// Dispatch 4: fused conv2 + bias/leakyrelu + ln2 + linear + mask -> ldp.
// 256 blocks x 256 thr (4 waves). Each wave owns TWO 32x32 col-chains
// (cob32 = nh and nh+4), so the block covers the full 32-row x 256-col tile
// and can LayerNorm in-register. No hraw write for layer 2.
// ---------------------------------------------------------------------------
__global__ __launch_bounds__(256, 2) void conv2_fused_kernel(
    const ushort_t* __restrict__ h1, const ushort_t* __restrict__ w2,
    const float* __restrict__ c2b, const float* __restrict__ g2,
    const float* __restrict__ b2, const float* __restrict__ lw,
    const float* __restrict__ lb, const unsigned char* __restrict__ mask,
    float* __restrict__ ldp) {
  constexpr int CI = 256;
  constexpr int ROWS = 36, LDSTRIDE = 136;
  __shared__ ushort_t sA[ROWS * LDSTRIDE];
  __shared__ float sred[32][4];
  __shared__ float s2red[32][4];
  __shared__ float smu[32];
  __shared__ float srs[32];

  const int mt = blockIdx.x;                  // 0..255
  const int b = mt >> 4, t0 = (mt & 15) * 32;
  const int tid = threadIdx.x;
  const int l = tid & 63, nh = tid >> 6;      // wave 0..3
  const int lm = l & 31, lq = l >> 5;

  f32x16 acc0, acc1;
#pragma unroll
  for (int i = 0; i < 16; ++i) { acc0[i] = 0.f; acc1[i] = 0.f; }

  const ushort_t* pB0 = w2 + (size_t)nh * 512 + l * 8;        // cob32 = nh
  const ushort_t* pB1 = w2 + (size_t)(nh + 4) * 512 + l * 8;  // cob32 = nh+4

#pragma unroll 1
  for (int chunk = 0; chunk < 2; ++chunk) {
    {
      const int cibase = chunk * 128;
#pragma unroll 1
      for (int i = 0; i < 9; ++i) {
        const int p = i * 256 + tid;
        const int r = p >> 6, c2 = (p & 63) * 2;
        const int t = t0 - 2 + r;
        unsigned hv = 0;
        if ((unsigned)t < (unsigned)Tn) {
          const size_t src = (size_t)(b * Tn + t) * CI + cibase + c2;
          hv = *(const unsigned*)(h1 + src);
        }
        const int sw = ((r >> 3) & 3) << 3;
        *(unsigned*)&sA[r * LDSTRIDE + (c2 ^ sw)] = hv;
      }
    }
    __syncthreads();

#pragma unroll 1
    for (int ksh = 0; ksh < 5; ++ksh) {
      const int r = lm + ksh;
      const int sw = ((r >> 3) & 3) << 3;
      const size_t bbase = (size_t)((ksh * (CI / 16) + chunk * 8) * 8) * 512;
#pragma unroll
      for (int kk = 0; kk < 8; ++kk) {
        const int c = (kk * 16 + lq * 8) ^ sw;
        const bf16x8 a = *(const bf16x8*)&sA[r * LDSTRIDE + c];
        const bf16x8 bv0 = *(const bf16x8*)(pB0 + bbase + (size_t)kk * 8 * 512);
        const bf16x8 bv1 = *(const bf16x8*)(pB1 + bbase + (size_t)kk * 8 * 512);
        acc0 = __builtin_amdgcn_mfma_f32_32x32x16_bf16(a, bv0, acc0, 0, 0, 0);
        acc1 = __builtin_amdgcn_mfma_f32_32x32x16_bf16(a, bv1, acc1, 0, 0, 0);
      }
    }
    __syncthreads();
  }

  // ---- epilogue: bias + leakyrelu + LN(256) + linear + mask ----
  // chain0 cols: nh*32 + lm ; chain1 cols: 128 + nh*32 + lm
  const int col0 = nh * 32 + lm;
  const int col1 = col0 + 128;
  const float bi0 = c2b[col0], bi1 = c2b[col1];
  float s[16], s2v[16];
#pragma unroll
  for (int rg = 0; rg < 16; ++rg) {
    float a0 = acc0[rg] + bi0;
    float a1 = acc1[rg] + bi1;
    a0 = (a0 > 0.f) ? a0 : LRELU * a0;
    a1 = (a1 > 0.f) ? a1 : LRELU * a1;
    acc0[rg] = a0;
    acc1[rg] = a1;
    s[rg] = a0 + a1;
    s2v[rg] = a0 * a0 + a1 * a1;
  }
#pragma unroll
  for (int off = 16; off >= 1; off >>= 1) {
#pragma unroll
    for (int rg = 0; rg < 16; ++rg) {
      s[rg] += __shfl_xor(s[rg], off);
      s2v[rg] += __shfl_xor(s2v[rg], off);
    }
  }
  if (lm == 0) {
#pragma unroll
    for (int rg = 0; rg < 16; ++rg) {
      const int row = (rg & 3) + 8 * (rg >> 2) + 4 * lq;
      sred[row][nh] = s[rg];
      s2red[row][nh] = s2v[rg];
    }
  }
  __syncthreads();
  if (tid < 32) {
    float a = 0.f, q = 0.f;
#pragma unroll
    for (int w = 0; w < 4; ++w) { a += sred[tid][w]; q += s2red[tid][w]; }
    const float mu = a * (1.f / 256.f);
    const float var = q * (1.f / 256.f) - mu * mu;
    smu[tid] = mu;
    srs[tid] = rsqrtf(var + EPSV);
  }
  __syncthreads();

  const float g0 = g2[col0], g1v = g2[col1];
  const float be0 = b2[col0], be1 = b2[col1];
  const float w0 = lw[col0], w1v = lw[col1];
  float d[16];
#pragma unroll
  for (int rg = 0; rg < 16; ++rg) {
    const int row = (rg & 3) + 8 * (rg >> 2) + 4 * lq;
    const float mu = smu[row], rs = srs[row];
    const float h0 = (acc0[rg] - mu) * rs * g0 + be0;
    const float h1v = (acc1[rg] - mu) * rs * g1v + be1;
    d[rg] = h0 * w0 + h1v * w1v;
  }
#pragma unroll
  for (int off = 16; off >= 1; off >>= 1) {
#pragma unroll
    for (int rg = 0; rg < 16; ++rg) d[rg] += __shfl_xor(d[rg], off);
  }
  __syncthreads();                           // sred free for reuse
  if (lm == 0) {
#pragma unroll
    for (int rg = 0; rg < 16; ++rg) {
      const int row = (rg & 3) + 8 * (rg >> 2) + 4 * lq;
      sred[row][nh] = d[rg];
    }
  }
  __syncthreads();
  if (tid < 32) {
    float a = lb[0];
#pragma unroll
    for (int w = 0; w < 4; ++w) a += sred[tid][w];
    const int grow = b * Tn + t0 + tid;
    ldp[grow] = mask[grow] ? 0.f : a;
  }
}

// ---------------------------------------------------------------------------
// Dispatch 1: weight prep (blocks 0..239, 8 frags/block) + build_idx
// (blocks 240..255). 512 threads. Verbatim R9.
// ---------------------------------------------------------------------------
__global__ __launch_bounds__(512) void prep_kernel(
    const float* __restrict__ w1src, const float* __restrict__ w2src,
    ushort_t* __restrict__ w1dst, ushort_t* __restrict__ w2dst,
    const int* __restrict__ dur, int* __restrict__ idx) {
  __shared__ int wsum[8];
  const int blk = blockIdx.x;
  const int tid = threadIdx.x;
  if (blk < 240) {
    const float* src;
    ushort_t* dst;
    int CI, fr, sh;
    const int wv = tid >> 6, l = tid & 63;
    if (blk < 160) { src = w1src; dst = w1dst; CI = 512; sh = 5; fr = blk * 8 + wv; }
    else           { src = w2src; dst = w2dst; CI = 256; sh = 4; fr = (blk - 160) * 8 + wv; }
    const int cob32 = fr & 7;
    const int t = fr >> 3;
    const int ksh = t >> sh;
    const int ci16 = t & ((1 << sh) - 1);
    const int ci = ci16 * 16 + (l >> 5) * 8;
    const int co = cob32 * 32 + (l & 31);
    ushort_t v[8];
#pragma unroll
    for (int j = 0; j < 8; ++j)
      v[j] = f2bf(src[((size_t)(ksh * CI + ci + j)) * 256 + co]);
    u32x4 pack;
#pragma unroll
    for (int q = 0; q < 4; ++q)
      pack[q] = (unsigned)v[q * 2] | ((unsigned)v[q * 2 + 1] << 16);
    *(u32x4*)&dst[(size_t)fr * 512 + l * 8] = pack;
    return;
  }
  // ---- build_idx path ----
  const int b = blk - 240;
  const int lane = tid & 63, wv = tid >> 6;
  const int d = dur[b * Tn + tid];
  int v = d;
#pragma unroll
  for (int off = 1; off <= 32; off <<= 1) {
    const int t = __shfl_up(v, off);
    if (lane >= off) v += t;
  }
  if (lane == 63) wsum[wv] = v;
  __syncthreads();
  int woff = 0, total = 0;
#pragma unroll
  for (int i = 0; i < 8; ++i) {
    const int s = wsum[i];
    if (i < wv) woff += s;
    total += s;
  }
  const int end = v + woff;               // inclusive cumsum
  for (int p = end - d; p < end; ++p) idx[b * MAXMEL + p] = tid;
  for (int p = total + tid; p < MAXMEL; p += 512) idx[b * MAXMEL + p] = -1;
}

// ---------------------------------------------------------------------------
extern "C" void kernel_launch(void* const* d_in, const int* in_sizes, int n_in,
                              void* d_out, int out_size, void* d_ws, size_t ws_size,
                              hipStream_t stream) {
  const float* x     = (const float*)d_in[0];
  const float* x_res = (const float*)d_in[1];
  const int*   dur   = (const int*)d_in[2];
  const float* emb   = (const float*)d_in[3];
  const unsigned char* mask = (const unsigned char*)d_in[4];
  const float* c1w = (const float*)d_in[5];
  const float* c1b = (const float*)d_in[6];
  const float* g1  = (const float*)d_in[7];
  const float* b1  = (const float*)d_in[8];
  const float* c2w = (const float*)d_in[9];
  const float* c2b = (const float*)d_in[10];
  const float* g2  = (const float*)d_in[11];
  const float* b2  = (const float*)d_in[12];
  const float* lw  = (const float*)d_in[13];
  const float* lb  = (const float*)d_in[14];

  float* x_up   = (float*)d_out;
  float* ldp    = x_up + (size_t)Bn * MAXMEL * CIN1;
  float* emb_up = ldp + (size_t)Bn * Tn;

  // ws layout: idx 256KB | h1 4MB | w1 1.31MB | w2 0.66MB | hraw 8MB ≈ 14.5MB
  int* idx = (int*)d_ws;
  ushort_t* h1 = (ushort_t*)((char*)d_ws + (size_t)Bn * MAXMEL * 4);
  ushort_t* w1 = h1 + (size_t)NROWS * 256;
  ushort_t* w2 = w1 + (size_t)5 * 512 * 256;
  float* hraw = (float*)(w2 + (size_t)5 * 256 * 256);

  prep_kernel<<<256, 512, 0, stream>>>(c1w, c2w, w1, w2, dur, idx);
  conv1_gather_kernel<<<1536, 256, 0, stream>>>(
      x_res, w1, hraw, x, idx, x_up);
  ln1_emb_kernel<<<3072, 256, 0, stream>>>(
      hraw, c1b, g1, b1, h1, emb, idx, emb_up);
  conv2_fused_kernel<<<256, 256, 0, stream>>>(
      h1, w2, c2b, g2, b2, lw, lb, mask, ldp);
}

// Round 3
// 343.106 us; speedup vs baseline: 1.0627x; 1.0627x over previous
//
#include <hip/hip_runtime.h>

// LengthAdaptor: B=16, T=512, C_IN=512, C_HID=256, C_EMB=384, K=5, MAX_DUR=8
// Outputs (concat, f32): x_up [16,4096,512] | ldp [16,512] | emb_up [16,4096,384]
//
// R12: exact R9 structure (5 dispatches, proven fastest) with two in-place
// MLP fixes only:
//  (a) conv staging split into issue-phase (9 global loads in regs, unrolled)
//      + write-phase (cvt + swizzled ds_write) -- removes 9x serialized
//      load-use latency per chunk (G15 async-STAGE, no structural change).
//  (b) gathers unrolled x4 with batched idx prefetch -- 4 loads in flight
//      per thread instead of 1 (iteration counts are exact: 32 / 24).
// Grid, launch bounds, interleave ratios, LN kernels, prep: verbatim R9.

constexpr int Bn = 16, Tn = 512, CIN1 = 512, CHID = 256, CEMB = 384, MAXMEL = 4096;
constexpr int NROWS = Bn * Tn;
#define LRELU 0.3f
#define EPSV 1e-5f

typedef __attribute__((ext_vector_type(8))) short bf16x8;
typedef __attribute__((ext_vector_type(4))) float f32x4;
typedef __attribute__((ext_vector_type(16))) float f32x16;
typedef __attribute__((ext_vector_type(4))) unsigned int u32x4;
typedef unsigned short ushort_t;

static __device__ __forceinline__ ushort_t f2bf(float f) {
  unsigned u = __builtin_bit_cast(unsigned, f);
  unsigned r = (u + 0x7fffu + ((u >> 16) & 1u)) >> 16;  // RNE
  return (ushort_t)r;
}

// ---------------------------------------------------------------------------
// Conv MFMA body (32x32x16). Block tile 32 rows x 128 cols, 4 waves, each one
// 32x32 acc chain. A staged per 128-ci chunk in LDS (XOR swizzle); B direct
// from L2 (fragment-contiguous). Staging: issue-all-loads then write (R12a).
// ---------------------------------------------------------------------------
template <int CI, bool F32IN>
static __device__ __forceinline__ void conv_body(
    int mt, int ns,
    const float* __restrict__ xin, const ushort_t* __restrict__ inbf,
    const ushort_t* __restrict__ wB, float* __restrict__ hraw) {
  constexpr int NCHUNK = CI / 128;
  constexpr int ROWS = 36, LDSTRIDE = 136;
  __shared__ ushort_t sA[ROWS * LDSTRIDE];

  const int b = mt >> 4, t0 = (mt & 15) * 32;
  const int tid = threadIdx.x;
  const int l = tid & 63, nh = tid >> 6;
  const int lm = l & 31, lq = l >> 5;
  const int cob32 = ns * 4 + nh;

  f32x16 acc;
#pragma unroll
  for (int i = 0; i < 16; ++i) acc[i] = 0.f;

  const ushort_t* pB = wB + (size_t)cob32 * 512 + l * 8;

  const int rbase = tid >> 6;           // p = i*256+tid -> r = i*4 + (tid>>6)
  const int c2 = (tid & 63) * 2;

#pragma unroll 1
  for (int chunk = 0; chunk < NCHUNK; ++chunk) {
    {
      const int cibase = chunk * 128;
      float2 rf[9];
      unsigned ru[9];
      // issue phase: all 9 loads in flight
#pragma unroll
      for (int i = 0; i < 9; ++i) {
        const int r = i * 4 + rbase;
        const int t = t0 - 2 + r;
        if (F32IN) {
          rf[i] = make_float2(0.f, 0.f);
          if ((unsigned)t < (unsigned)Tn)
            rf[i] = *(const float2*)(xin + (size_t)(b * Tn + t) * CI + cibase + c2);
        } else {
          ru[i] = 0u;
          if ((unsigned)t < (unsigned)Tn)
            ru[i] = *(const unsigned*)(inbf + (size_t)(b * Tn + t) * CI + cibase + c2);
        }
      }
      // write phase: cvt + swizzled LDS write
#pragma unroll
      for (int i = 0; i < 9; ++i) {
        const int r = i * 4 + rbase;
        unsigned hv;
        if (F32IN)
          hv = (unsigned)f2bf(rf[i].x) | ((unsigned)f2bf(rf[i].y) << 16);
        else
          hv = ru[i];
        const int sw = ((r >> 3) & 3) << 3;
        *(unsigned*)&sA[r * LDSTRIDE + (c2 ^ sw)] = hv;
      }
    }
    __syncthreads();

#pragma unroll 1
    for (int ksh = 0; ksh < 5; ++ksh) {
      const int r = lm + ksh;
      const int sw = ((r >> 3) & 3) << 3;
      const size_t bbase = (size_t)((ksh * (CI / 16) + chunk * 8) * 8) * 512;
#pragma unroll
      for (int kk = 0; kk < 8; ++kk) {
        const int c = (kk * 16 + lq * 8) ^ sw;
        const bf16x8 a = *(const bf16x8*)&sA[r * LDSTRIDE + c];
        const bf16x8 bv = *(const bf16x8*)(pB + bbase + (size_t)kk * 8 * 512);
        acc = __builtin_amdgcn_mfma_f32_32x32x16_bf16(a, bv, acc, 0, 0, 0);
      }
    }
    __syncthreads();
  }

  // D: col = lane&31, row = (reg&3) + 8*(reg>>2) + 4*(lane>>5)
  const int col = ns * 128 + nh * 32 + lm;
  float* pOut = hraw + (size_t)(b * Tn + t0) * 256 + col;
#pragma unroll
  for (int reg = 0; reg < 16; ++reg) {
    const int row = (reg & 3) + 8 * (reg >> 2) + 4 * lq;
    pOut[(size_t)row * 256] = acc[reg];
  }
}

// ---------------------------------------------------------------------------
// Dispatch 2: conv1 (blk%3==0, 512 blocks) + x_up gather (1024 blocks).
// Grid 1536. Gather unrolled x4 (R12b).
// ---------------------------------------------------------------------------
__global__ __launch_bounds__(256, 2) void conv1_gather_kernel(
    const float* __restrict__ x_res, const ushort_t* __restrict__ w1,
    float* __restrict__ hraw,
    const float* __restrict__ x, const int* __restrict__ idx,
    float* __restrict__ x_up) {
  const int blk = blockIdx.x;
  if (blk % 3 == 0) {
    const int cid = blk / 3;              // 0..511
    conv_body<512, true>(cid & 255, cid >> 8, x_res, nullptr, w1, hraw);
    return;
  }
  // ---- x_up gather: 1024 blocks, 8,388,608 f32x4 units = 32 iters exact ----
  const int gid = blk - 1 - blk / 3;      // 0..1023
  const f32x4* x4 = (const f32x4*)x;
  f32x4* xu4 = (f32x4*)x_up;
  const int tid0 = gid * 256 + threadIdx.x;
  constexpr int stride = 1024 * 256;
  const f32x4 z = (f32x4){0.f, 0.f, 0.f, 0.f};
#pragma unroll 1
  for (int k0 = 0; k0 < 32; k0 += 4) {
    int tv[4];
#pragma unroll
    for (int j = 0; j < 4; ++j)
      tv[j] = idx[(tid0 + (k0 + j) * stride) >> 7];
    f32x4 v[4];
#pragma unroll
    for (int j = 0; j < 4; ++j) {
      const int u = tid0 + (k0 + j) * stride;
      const int i = u & 127;
      const int b = u >> 19;              // (u>>7)>>12
      v[j] = (tv[j] >= 0) ? x4[((b << 9) + tv[j]) * 128 + i] : z;
    }
#pragma unroll
    for (int j = 0; j < 4; ++j)
      __builtin_nontemporal_store(v[j], &xu4[tid0 + (k0 + j) * stride]);
  }
}

// ---------------------------------------------------------------------------
// Dispatch 4: conv2 (blk%3==0, 512 blocks) + emb_up gather (1024 blocks).
// Gather unrolled x4 (R12b).
// ---------------------------------------------------------------------------
__global__ __launch_bounds__(256, 2) void conv2_gather_kernel(
    const ushort_t* __restrict__ h1, const ushort_t* __restrict__ w2,
    float* __restrict__ hraw,
    const float* __restrict__ emb, const int* __restrict__ idx,
    float* __restrict__ emb_up) {
  const int blk = blockIdx.x;
  if (blk % 3 == 0) {
    const int cid = blk / 3;
    conv_body<256, false>(cid & 255, cid >> 8, nullptr, h1, w2, hraw);
    return;
  }
  // ---- emb_up gather: 1024 blocks, 6,291,456 f32x4 units = 24 iters exact ----
  const int gid = blk - 1 - blk / 3;
  const f32x4* e4 = (const f32x4*)emb;
  f32x4* eu4 = (f32x4*)emb_up;
  const int tid0 = gid * 256 + threadIdx.x;
  constexpr int stride = 1024 * 256;
  const f32x4 z = (f32x4){0.f, 0.f, 0.f, 0.f};
#pragma unroll 1
  for (int k0 = 0; k0 < 24; k0 += 4) {
    int tv[4];
    int bp[4];
#pragma unroll
    for (int j = 0; j < 4; ++j) {
      const int u = tid0 + (k0 + j) * stride;
      bp[j] = u / 96;
      tv[j] = idx[bp[j]];
    }
    f32x4 v[4];
#pragma unroll
    for (int j = 0; j < 4; ++j) {
      const int u = tid0 + (k0 + j) * stride;
      const int i = u - bp[j] * 96;
      const int b = bp[j] >> 12;
      v[j] = (tv[j] >= 0) ? e4[((b << 9) + tv[j]) * 96 + i] : z;
    }
#pragma unroll
    for (int j = 0; j < 4; ++j)
      __builtin_nontemporal_store(v[j], &eu4[tid0 + (k0 + j) * stride]);
  }
}

// ---------------------------------------------------------------------------
// bias + leaky-relu + LayerNorm. One wave per row, grid 2048. Verbatim R9.
// FINAL=false: emit h1 bf16. FINAL=true: fused linear(256->1) + mask -> ldp.
// ---------------------------------------------------------------------------
template <bool FINAL>
__global__ __launch_bounds__(256) void ln_kernel(
    const float* __restrict__ hraw,       // [8192][256] f32
    const float* __restrict__ bias, const float* __restrict__ g,
    const float* __restrict__ be, ushort_t* __restrict__ h1,
    const float* __restrict__ lw, const float* __restrict__ lb,
    const unsigned char* __restrict__ mask, float* __restrict__ ldp) {
  const int row = blockIdx.x * 4 + (threadIdx.x >> 6);
  const int l = threadIdx.x & 63;
  const f32x4 p = ((const f32x4*)hraw)[row * 64 + l];
  const f32x4 bi = ((const f32x4*)bias)[l];
  float v0 = p.x + bi.x, v1 = p.y + bi.y, v2 = p.z + bi.z, v3 = p.w + bi.w;
  v0 = (v0 > 0.f) ? v0 : LRELU * v0;
  v1 = (v1 > 0.f) ? v1 : LRELU * v1;
  v2 = (v2 > 0.f) ? v2 : LRELU * v2;
  v3 = (v3 > 0.f) ? v3 : LRELU * v3;
  float s = v0 + v1 + v2 + v3;
  float s2 = v0 * v0 + v1 * v1 + v2 * v2 + v3 * v3;
#pragma unroll
  for (int off = 32; off >= 1; off >>= 1) {
    s += __shfl_xor(s, off);
    s2 += __shfl_xor(s2, off);
  }
  const float mu = s * (1.f / 256.f);
  const float var = s2 * (1.f / 256.f) - mu * mu;
  const float rs = rsqrtf(var + EPSV);
  const f32x4 gg = ((const f32x4*)g)[l];
  const f32x4 bb = ((const f32x4*)be)[l];
  const float h0 = (v0 - mu) * rs * gg.x + bb.x;
  const float h1v = (v1 - mu) * rs * gg.y + bb.y;
  const float h2 = (v2 - mu) * rs * gg.z + bb.z;
  const float h3 = (v3 - mu) * rs * gg.w + bb.w;
  if (!FINAL) {
    ushort4 uh;
    uh.x = f2bf(h0); uh.y = f2bf(h1v); uh.z = f2bf(h2); uh.w = f2bf(h3);
    ((ushort4*)h1)[row * 64 + l] = uh;
  } else {
    const f32x4 lv = ((const f32x4*)lw)[l];
    float d = h0 * lv.x + h1v * lv.y + h2 * lv.z + h3 * lv.w;
#pragma unroll
    for (int off = 32; off >= 1; off >>= 1) d += __shfl_xor(d, off);
    if (l == 0) {
      float val = d + lb[0];
      if (mask[row]) val = 0.f;
      ldp[row] = val;
    }
  }
}

// ---------------------------------------------------------------------------
// Dispatch 1: weight prep (blocks 0..239, 8 frags/block) + build_idx
// (blocks 240..255). 512 threads. Verbatim R9.
// ---------------------------------------------------------------------------
__global__ __launch_bounds__(512) void prep_kernel(
    const float* __restrict__ w1src, const float* __restrict__ w2src,
    ushort_t* __restrict__ w1dst, ushort_t* __restrict__ w2dst,
    const int* __restrict__ dur, int* __restrict__ idx) {
  __shared__ int wsum[8];
  const int blk = blockIdx.x;
  const int tid = threadIdx.x;
  if (blk < 240) {
    const float* src;
    ushort_t* dst;
    int CI, fr, sh;
    const int wv = tid >> 6, l = tid & 63;
    if (blk < 160) { src = w1src; dst = w1dst; CI = 512; sh = 5; fr = blk * 8 + wv; }
    else           { src = w2src; dst = w2dst; CI = 256; sh = 4; fr = (blk - 160) * 8 + wv; }
    const int cob32 = fr & 7;
    const int t = fr >> 3;
    const int ksh = t >> sh;
    const int ci16 = t & ((1 << sh) - 1);
    const int ci = ci16 * 16 + (l >> 5) * 8;
    const int co = cob32 * 32 + (l & 31);
    ushort_t v[8];
#pragma unroll
    for (int j = 0; j < 8; ++j)
      v[j] = f2bf(src[((size_t)(ksh * CI + ci + j)) * 256 + co]);
    u32x4 pack;
#pragma unroll
    for (int q = 0; q < 4; ++q)
      pack[q] = (unsigned)v[q * 2] | ((unsigned)v[q * 2 + 1] << 16);
    *(u32x4*)&dst[(size_t)fr * 512 + l * 8] = pack;
    return;
  }
  // ---- build_idx path ----
  const int b = blk - 240;
  const int lane = tid & 63, wv = tid >> 6;
  const int d = dur[b * Tn + tid];
  int v = d;
#pragma unroll
  for (int off = 1; off <= 32; off <<= 1) {
    const int t = __shfl_up(v, off);
    if (lane >= off) v += t;
  }
  if (lane == 63) wsum[wv] = v;
  __syncthreads();
  int woff = 0, total = 0;
#pragma unroll
  for (int i = 0; i < 8; ++i) {
    const int s = wsum[i];
    if (i < wv) woff += s;
    total += s;
  }
  const int end = v + woff;               // inclusive cumsum
  for (int p = end - d; p < end; ++p) idx[b * MAXMEL + p] = tid;
  for (int p = total + tid; p < MAXMEL; p += 512) idx[b * MAXMEL + p] = -1;
}

// ---------------------------------------------------------------------------
extern "C" void kernel_launch(void* const* d_in, const int* in_sizes, int n_in,
                              void* d_out, int out_size, void* d_ws, size_t ws_size,
                              hipStream_t stream) {
  const float* x     = (const float*)d_in[0];
  const float* x_res = (const float*)d_in[1];
  const int*   dur   = (const int*)d_in[2];
  const float* emb   = (const float*)d_in[3];
  const unsigned char* mask = (const unsigned char*)d_in[4];
  const float* c1w = (const float*)d_in[5];
  const float* c1b = (const float*)d_in[6];
  const float* g1  = (const float*)d_in[7];
  const float* b1  = (const float*)d_in[8];
  const float* c2w = (const float*)d_in[9];
  const float* c2b = (const float*)d_in[10];
  const float* g2  = (const float*)d_in[11];
  const float* b2  = (const float*)d_in[12];
  const float* lw  = (const float*)d_in[13];
  const float* lb  = (const float*)d_in[14];

  float* x_up   = (float*)d_out;
  float* ldp    = x_up + (size_t)Bn * MAXMEL * CIN1;
  float* emb_up = ldp + (size_t)Bn * Tn;

  // ws layout: idx 256KB | h1 4MB | w1 1.31MB | w2 0.66MB | hraw 8MB ≈ 14.5MB
  int* idx = (int*)d_ws;
  ushort_t* h1 = (ushort_t*)((char*)d_ws + (size_t)Bn * MAXMEL * 4);
  ushort_t* w1 = h1 + (size_t)NROWS * 256;
  ushort_t* w2 = w1 + (size_t)5 * 512 * 256;
  float* hraw = (float*)(w2 + (size_t)5 * 256 * 256);

  prep_kernel<<<256, 512, 0, stream>>>(c1w, c2w, w1, w2, dur, idx);
  conv1_gather_kernel<<<1536, 256, 0, stream>>>(
      x_res, w1, hraw, x, idx, x_up);
  ln_kernel<false><<<NROWS / 4, 256, 0, stream>>>(
      hraw, c1b, g1, b1, h1, nullptr, nullptr, nullptr, nullptr);
  conv2_gather_kernel<<<1536, 256, 0, stream>>>(
      h1, w2, hraw, emb, idx, emb_up);
  ln_kernel<true><<<NROWS / 4, 256, 0, stream>>>(
      hraw, c2b, g2, b2, nullptr, lw, lb, mask, ldp);
}